// Round 2
// baseline (593.644 us; speedup 1.0000x reference)
//
#include <hip/hip_runtime.h>
#include <stdint.h>

#define B_ 4
#define L_ 4096
#define H_ 8
#define D_ 64
#define S_ 45
#define U_ 45
#define BH_ 32
#define STRIDE_ (H_*D_)            // 512 floats between consecutive l
#define BSTR_ ((size_t)L_*H_*D_)   // 2097152 floats per batch

// index_sample declared int64 in the reference; harness may pass int32 or int64.
// Detect layout from data: int64 => odd int32 slots (high words) all zero.
__device__ __forceinline__ bool detect_idx64(const int* idxp){
    bool z = true;
    #pragma unroll
    for (int i = 1; i < 32; i += 2) z = z && (idxp[i] == 0);
    return z;
}

// ---------- kernel A: M[bh][q] = max_s(dot) - sum_s(dot)/L ----------
__global__ __launch_bounds__(256) void kM(const float* __restrict__ Qb,
                                          const float* __restrict__ Kb,
                                          const int* __restrict__ idxp,
                                          float* __restrict__ Mout){
    int bh = blockIdx.y; int b = bh >> 3, h = bh & 7;
    int q  = blockIdx.x * 256 + threadIdx.x;
    bool idx64 = detect_idx64(idxp);

    const float4* Q4 = (const float4*)(Qb + (size_t)b*BSTR_ + (size_t)q*STRIDE_ + h*D_);
    float4 qf[16];
    #pragma unroll
    for (int c = 0; c < 16; c++) qf[c] = Q4[c];

    const size_t kbase = (size_t)b*BSTR_ + (size_t)h*D_;
    float mx = -1e30f, sm = 0.f;
    for (int s = 0; s < S_; s++){
        int flat = q * S_ + s;
        int ki = idx64 ? idxp[2*flat] : idxp[flat];
        const float4* K4 = (const float4*)(Kb + kbase + (size_t)ki*STRIDE_);
        float acc = 0.f;
        #pragma unroll
        for (int c = 0; c < 16; c++){
            float4 kv = K4[c];
            acc = fmaf(qf[c].x, kv.x, acc);
            acc = fmaf(qf[c].y, kv.y, acc);
            acc = fmaf(qf[c].z, kv.z, acc);
            acc = fmaf(qf[c].w, kv.w, acc);
        }
        mx = fmaxf(mx, acc); sm += acc;
    }
    Mout[bh * L_ + q] = mx - sm * (1.0f / L_);
}

// ---------- kernel B: top-45 indices of M per (b,h) ----------
__global__ __launch_bounds__(256) void kTop(const float* __restrict__ M,
                                            int* __restrict__ Mtop){
    int bh = blockIdx.x;
    __shared__ float sv[L_];
    __shared__ float wv[4]; __shared__ int wi[4];
    const float* Mr = M + (size_t)bh * L_;
    for (int j = threadIdx.x; j < L_; j += 256) sv[j] = Mr[j];
    __syncthreads();
    for (int it = 0; it < U_; it++){
        float best = -1e30f; int bi = 0;
        #pragma unroll
        for (int j = 0; j < 16; j++){
            int id = threadIdx.x + 256*j; float v = sv[id];
            if (v > best){ best = v; bi = id; }
        }
        for (int off = 32; off; off >>= 1){
            float ov = __shfl_down(best, off); int oi = __shfl_down(bi, off);
            if (ov > best || (ov == best && oi < bi)){ best = ov; bi = oi; }
        }
        int w = threadIdx.x >> 6;
        if ((threadIdx.x & 63) == 0){ wv[w] = best; wi[w] = bi; }
        __syncthreads();
        if (threadIdx.x == 0){
            float gb = wv[0]; int gi = wi[0];
            for (int k = 1; k < 4; k++)
                if (wv[k] > gb || (wv[k] == gb && wi[k] < gi)){ gb = wv[k]; gi = wi[k]; }
            Mtop[bh*U_ + it] = gi; sv[gi] = -1e30f;
        }
        __syncthreads();
    }
}

// ---------- kernel C1: partial V sums over 256-row chunks ----------
__global__ __launch_bounds__(256) void kVsum(const float* __restrict__ Vb,
                                             float* __restrict__ partial){
    int bh = blockIdx.y, b = bh >> 3, h = bh & 7; int chunk = blockIdx.x; // 16
    int d8 = threadIdx.x & 7, sub = threadIdx.x >> 3;                    // 32 subs
    float acc[8];
    #pragma unroll
    for (int j = 0; j < 8; j++) acc[j] = 0.f;
    for (int i = 0; i < 8; i++){
        int l = chunk*256 + sub + 32*i;
        const float4* V4 = (const float4*)(Vb + (size_t)b*BSTR_ + (size_t)l*STRIDE_ + h*D_);
        float4 a = V4[d8*2], c4 = V4[d8*2+1];
        acc[0] += a.x;  acc[1] += a.y;  acc[2] += a.z;  acc[3] += a.w;
        acc[4] += c4.x; acc[5] += c4.y; acc[6] += c4.z; acc[7] += c4.w;
    }
    __shared__ float red[32][64];
    #pragma unroll
    for (int j = 0; j < 8; j++) red[sub][d8*8+j] = acc[j];
    __syncthreads();
    if (threadIdx.x < 64){
        float s = 0.f;
        for (int k = 0; k < 32; k++) s += red[k][threadIdx.x];
        partial[((size_t)bh*16 + chunk)*64 + threadIdx.x] = s;
    }
}

// ---------- kernel C2: mean = sum(partials)/L ----------
__global__ void kVmean(const float* __restrict__ partial, float* __restrict__ mean){
    int bh = blockIdx.x; int d = threadIdx.x; // 64 threads
    float s = 0.f;
    for (int c = 0; c < 16; c++) s += partial[((size_t)bh*16 + c)*64 + d];
    mean[bh*64 + d] = s * (1.0f / L_);
}

// ---------- kernel Z: zero the upd accumulator ----------
__global__ void kZero(float* __restrict__ upd){
    int t = blockIdx.x*256 + threadIdx.x;
    if (t < BH_*U_*D_) upd[t] = 0.f;
}

// ---------- kernel D1: scores[bh][u][k] = scale * Q[qi_u]·K[k] ----------
__global__ __launch_bounds__(256) void kScores(const float* __restrict__ Qb,
                                               const float* __restrict__ Kb,
                                               const int* __restrict__ Mtop,
                                               float* __restrict__ scores){
    int bh = blockIdx.y, b = bh >> 3, h = bh & 7; int kc = blockIdx.x; // 16
    __shared__ float qs[U_][64];
    for (int t = threadIdx.x; t < U_*16; t += 256){
        int u = t >> 4, c = t & 15;
        int qi = Mtop[bh*U_ + u];
        float4 v = ((const float4*)(Qb + (size_t)b*BSTR_ + (size_t)qi*STRIDE_ + h*D_))[c];
        *(float4*)&qs[u][c*4] = v;
    }
    __syncthreads();
    int k = kc*256 + threadIdx.x;
    float4 kf[16];
    const float4* K4 = (const float4*)(Kb + (size_t)b*BSTR_ + (size_t)k*STRIDE_ + h*D_);
    #pragma unroll
    for (int c = 0; c < 16; c++) kf[c] = K4[c];
    for (int u = 0; u < U_; u++){
        const float4* qr = (const float4*)qs[u];
        float acc = 0.f;
        #pragma unroll
        for (int c = 0; c < 16; c++){
            float4 qv = qr[c];
            acc = fmaf(qv.x, kf[c].x, acc);
            acc = fmaf(qv.y, kf[c].y, acc);
            acc = fmaf(qv.z, kf[c].z, acc);
            acc = fmaf(qv.w, kf[c].w, acc);
        }
        scores[((size_t)(bh*U_ + u))*L_ + k] = acc * 0.125f;
    }
}

// ---------- kernel D2: softmax over k, in place ----------
__global__ __launch_bounds__(256) void kSoftmax(float* __restrict__ scores){
    int row = blockIdx.x; // 0..1439
    float* S = scores + (size_t)row * L_;
    float v[16];
    float mx = -1e30f;
    #pragma unroll
    for (int j = 0; j < 16; j++){ v[j] = S[threadIdx.x + 256*j]; mx = fmaxf(mx, v[j]); }
    for (int off = 32; off; off >>= 1) mx = fmaxf(mx, __shfl_xor(mx, off));
    __shared__ float wred[4];
    int w = threadIdx.x >> 6;
    if ((threadIdx.x & 63) == 0) wred[w] = mx;
    __syncthreads();
    mx = fmaxf(fmaxf(wred[0], wred[1]), fmaxf(wred[2], wred[3]));
    float sum = 0.f;
    #pragma unroll
    for (int j = 0; j < 16; j++){ v[j] = __expf(v[j] - mx); sum += v[j]; }
    for (int off = 32; off; off >>= 1) sum += __shfl_xor(sum, off);
    __syncthreads();                 // protect wred reuse
    if ((threadIdx.x & 63) == 0) wred[w] = sum;
    __syncthreads();
    float total = wred[0] + wred[1] + wred[2] + wred[3];
    float inv = 1.0f / total;
    #pragma unroll
    for (int j = 0; j < 16; j++) S[threadIdx.x + 256*j] = v[j] * inv;
}

// ---------- kernel D3: upd[bh][u][d] += P[bh][u][kchunk] @ V[kchunk][d] ----------
__global__ __launch_bounds__(256) void kPV(const float* __restrict__ Vb,
                                           const float* __restrict__ P,
                                           float* __restrict__ upd){
    int bh = blockIdx.y, b = bh >> 3, h = bh & 7; int kc = blockIdx.x; // 8 chunks x 512
    __shared__ float Pl[8][512];       // 16 KB
    __shared__ float red[4][8][64];    // 8 KB
    int d8 = threadIdx.x & 7, ks = threadIdx.x >> 3;  // ks 0..31
    int wv = threadIdx.x >> 6, lane = threadIdx.x & 63;

    for (int g = 0; g < 6; g++){
        int u0 = g*8; int nu = (U_ - u0 < 8) ? (U_ - u0) : 8;
        __syncthreads();   // previous iteration done with Pl/red
        for (int r = 0; r < nu; r++){
            const float* Pr = P + ((size_t)(bh*U_ + u0 + r))*L_ + kc*512;
            Pl[r][threadIdx.x]       = Pr[threadIdx.x];
            Pl[r][threadIdx.x + 256] = Pr[threadIdx.x + 256];
        }
        __syncthreads();

        float acc[8][8];
        #pragma unroll
        for (int r = 0; r < 8; r++)
            #pragma unroll
            for (int j = 0; j < 8; j++) acc[r][j] = 0.f;

        for (int i = 0; i < 16; i++){
            int k = ks + 32*i;
            const float4* V4 = (const float4*)(Vb + (size_t)b*BSTR_ +
                        (size_t)(kc*512 + k)*STRIDE_ + h*D_);
            float4 va = V4[d8*2], vb = V4[d8*2+1];
            float vf[8] = {va.x, va.y, va.z, va.w, vb.x, vb.y, vb.z, vb.w};
            #pragma unroll
            for (int r = 0; r < 8; r++){
                float p = Pl[r][k];    // rows >= nu hold stale-but-finite data; ignored below
                #pragma unroll
                for (int j = 0; j < 8; j++) acc[r][j] = fmaf(p, vf[j], acc[r][j]);
            }
        }
        // butterfly across ks within wave (lane bits 3..5)
        #pragma unroll
        for (int off = 8; off <= 32; off <<= 1)
            #pragma unroll
            for (int r = 0; r < 8; r++)
                #pragma unroll
                for (int j = 0; j < 8; j++) acc[r][j] += __shfl_xor(acc[r][j], off);
        if (lane < 8){  // one lane per d8 group holds the wave sum
            for (int r = 0; r < 8; r++)
                #pragma unroll
                for (int j = 0; j < 8; j++) red[wv][r][d8*8+j] = acc[r][j];
        }
        __syncthreads();
        for (int t = threadIdx.x; t < nu*64; t += 256){
            int r = t >> 6, d = t & 63;
            float s = red[0][r][d] + red[1][r][d] + red[2][r][d] + red[3][r][d];
            atomicAdd(&upd[((size_t)(bh*U_) + u0 + r)*64 + d], s);
        }
    }
}

// ---------- kernel E: fill output with the V-mean everywhere ----------
__global__ __launch_bounds__(256) void kFill(const float* __restrict__ mean,
                                             float* __restrict__ out){
    size_t t = (size_t)blockIdx.x*256 + threadIdx.x;   // one float4 each; 2,097,152 total
    int d16 = (int)(t & 15); int h = (int)((t >> 4) & 7); int b = (int)(t >> 19);
    int bh = b*8 + h;
    float4 o = *(const float4*)(mean + bh*64 + d16*4);
    ((float4*)out)[t] = o;
}

// ---------- kernel D4: scatter the 45 attended rows per (b,h) ----------
__global__ void kWriteRows(const float* __restrict__ upd,
                           const int* __restrict__ Mtop,
                           float* __restrict__ out){
    int bh = blockIdx.y, u = blockIdx.x; int b = bh >> 3, h = bh & 7;
    int qi = Mtop[bh*U_ + u];
    int d = threadIdx.x;  // 64
    float vv = upd[((size_t)(bh*U_) + u)*64 + d];
    out[(size_t)b*BSTR_ + (size_t)qi*STRIDE_ + h*D_ + d] = vv;
}

extern "C" void kernel_launch(void* const* d_in, const int* in_sizes, int n_in,
                              void* d_out, int out_size, void* d_ws, size_t ws_size,
                              hipStream_t stream) {
    const float* Qb  = (const float*)d_in[0];
    const float* Kb  = (const float*)d_in[1];
    const float* Vb  = (const float*)d_in[2];
    const int*   idx = (const int*)d_in[3];
    float* out = (float*)d_out;

    float* ws = (float*)d_ws;
    // ws layout (float offsets)
    float* scores   = ws;                         // 32*45*4096   = 5,898,240
    float* M        = ws + 5898240;               // 131072
    int*   Mtop     = (int*)(ws + 6029312);       // 1440 (pad to 2048)
    float* partialC = ws + 6031360;               // 32*16*64 = 32768
    float* mean     = ws + 6064128;               // 2048
    float* upd      = ws + 6066176;               // 32*45*64 = 92160
    // total = 6,158,336 floats = 24.6 MB

    dim3 blk256(256);
    kM        <<<dim3(16, 32), blk256, 0, stream>>>(Qb, Kb, idx, M);
    kTop      <<<dim3(32),     blk256, 0, stream>>>(M, Mtop);
    kVsum     <<<dim3(16, 32), blk256, 0, stream>>>(Vb, partialC);
    kVmean    <<<dim3(32),     dim3(64), 0, stream>>>(partialC, mean);
    kZero     <<<dim3(360),    blk256, 0, stream>>>(upd);
    kScores   <<<dim3(16, 32), blk256, 0, stream>>>(Qb, Kb, Mtop, scores);
    kSoftmax  <<<dim3(1440),   blk256, 0, stream>>>(scores);
    kPV       <<<dim3(8, 32),  blk256, 0, stream>>>(Vb, scores, upd);
    kFill     <<<dim3(8192),   blk256, 0, stream>>>(mean, out);
    kWriteRows<<<dim3(45, 32), dim3(64), 0, stream>>>(upd, Mtop, out);
}

// Round 3
// 353.147 us; speedup vs baseline: 1.6810x; 1.6810x over previous
//
#include <hip/hip_runtime.h>
#include <stdint.h>

#define B_ 4
#define L_ 4096
#define H_ 8
#define D_ 64
#define S_ 45
#define U_ 45
#define BH_ 32
#define STRIDE_ (H_*D_)            // 512 floats between consecutive l
#define BSTR_ ((size_t)L_*H_*D_)   // 2097152 floats per batch

// index_sample declared int64 in the reference; harness may pass int32 or int64.
// Detect layout from data: int64 => odd int32 slots (high words) all zero.
__device__ __forceinline__ bool detect_idx64(const int* idxp){
    bool z = true;
    #pragma unroll
    for (int i = 1; i < 32; i += 2) z = z && (idxp[i] == 0);
    return z;
}

// ---------- kernel A: M[bh][q] = max_s(dot) - sum_s(dot)/L ----------
// Wave-cooperative: 16 lanes per (q,s) gather -> one 256B coalesced row read
// (2 cache-line requests vs 16 in the per-lane version). XCD-aware swizzle:
// xcd = g&7 sees only bh in [4*xcd, 4*xcd+3], bh slowest -> ~1-2MB L2 set.
__global__ __launch_bounds__(256) void kM(const float* __restrict__ Qb,
                                          const float* __restrict__ Kb,
                                          const int* __restrict__ idxp,
                                          float* __restrict__ Mout){
    int g = blockIdx.x;                 // 0..2047
    int xcd  = g & 7;
    int slot = g >> 3;                  // 0..255
    int bh   = xcd*4 + (slot >> 6);     // bh varies slowest within an XCD
    int chunk= slot & 63;               // 64-query chunk
    int b = bh >> 3, h = bh & 7;
    int q0 = chunk * 64;
    bool idx64 = detect_idx64(idxp);

    __shared__ float qs[64][64];        // 16 KB Q tile
    for (int i = threadIdx.x; i < 64*16; i += 256){
        int qrow = i >> 4, c = i & 15;
        float4 v = ((const float4*)(Qb + (size_t)b*BSTR_ + (size_t)(q0+qrow)*STRIDE_ + h*D_))[c];
        *(float4*)&qs[qrow][c*4] = v;
    }
    __syncthreads();

    int lane16 = threadIdx.x & 15, gid = threadIdx.x >> 4;   // 16 groups of 16
    const float* kbase = Kb + (size_t)b*BSTR_ + h*D_;

    for (int qq = 0; qq < 4; qq++){
        int ql = gid*4 + qq;            // 0..63
        int qg = q0 + ql;
        float4 qf = *(const float4*)&qs[ql][lane16*4];
        float mx = -1e30f, sm = 0.f;
        #pragma unroll 5
        for (int s = 0; s < S_; s++){
            int flat = qg * S_ + s;
            int ki = idx64 ? idxp[2*flat] : idxp[flat];
            float4 kv = *(const float4*)(kbase + (size_t)ki*STRIDE_ + lane16*4);
            float p = qf.x*kv.x;
            p = fmaf(qf.y, kv.y, p);
            p = fmaf(qf.z, kv.z, p);
            p = fmaf(qf.w, kv.w, p);
            p += __shfl_xor(p, 1);
            p += __shfl_xor(p, 2);
            p += __shfl_xor(p, 4);
            p += __shfl_xor(p, 8);
            mx = fmaxf(mx, p); sm += p;
        }
        if (lane16 == 0) Mout[bh * L_ + qg] = mx - sm * (1.0f / L_);
    }
}

// ---------- kernel B: top-45 indices of M per (b,h), incremental rescan ----------
__global__ __launch_bounds__(256) void kTop(const float* __restrict__ M,
                                            int* __restrict__ Mtop){
    int bh = blockIdx.x;
    int t = threadIdx.x;
    __shared__ float sv[L_];
    __shared__ float lb[256]; __shared__ int lbi[256];
    __shared__ float wv[4];  __shared__ int wi[4];
    __shared__ int sgi;
    const float* Mr = M + (size_t)bh * L_;
    for (int j = t; j < L_; j += 256) sv[j] = Mr[j];
    __syncthreads();
    {   // per-thread local argmax over ids t, t+256, ..., t+3840 (ascending -> lowest-id tie)
        float best = -1e30f; int bi = t;
        #pragma unroll
        for (int j = 0; j < 16; j++){
            int id = t + 256*j; float v = sv[id];
            if (v > best){ best = v; bi = id; }
        }
        lb[t] = best; lbi[t] = bi;
    }
    __syncthreads();
    for (int it = 0; it < U_; it++){
        float best = lb[t]; int bi = lbi[t];
        for (int off = 32; off; off >>= 1){
            float ov = __shfl_down(best, off); int oi = __shfl_down(bi, off);
            if (ov > best || (ov == best && oi < bi)){ best = ov; bi = oi; }
        }
        int w = t >> 6;
        if ((t & 63) == 0){ wv[w] = best; wi[w] = bi; }
        __syncthreads();
        if (t == 0){
            float gb = wv[0]; int gi = wi[0];
            for (int k = 1; k < 4; k++)
                if (wv[k] > gb || (wv[k] == gb && wi[k] < gi)){ gb = wv[k]; gi = wi[k]; }
            Mtop[bh*U_ + it] = gi; sgi = gi;
        }
        __syncthreads();
        int gi = sgi;
        if (t == (gi & 255)){           // owner re-scans its 16 entries
            sv[gi] = -1e30f;
            float nb = -1e30f; int nbi = t;
            #pragma unroll
            for (int j = 0; j < 16; j++){
                int id = t + 256*j; float v = sv[id];
                if (v > nb){ nb = v; nbi = id; }
            }
            lb[t] = nb; lbi[t] = nbi;
        }
        __syncthreads();
    }
}

// ---------- kernel Z: zero mean + upd accumulators (contiguous range) ----------
__global__ void kZero(float* __restrict__ p, int n){
    int t = blockIdx.x*256 + threadIdx.x;
    if (t < n) p[t] = 0.f;
}

// ---------- kernel C: V column sums -> atomicAdd into mean (holds SUM; scaled in kFill) ----------
__global__ __launch_bounds__(256) void kVsum(const float* __restrict__ Vb,
                                             float* __restrict__ mean){
    int bh = blockIdx.y, b = bh >> 3, h = bh & 7; int chunk = blockIdx.x; // 16
    int d8 = threadIdx.x & 7, sub = threadIdx.x >> 3;                    // 32 subs
    float acc[8];
    #pragma unroll
    for (int j = 0; j < 8; j++) acc[j] = 0.f;
    for (int i = 0; i < 8; i++){
        int l = chunk*256 + sub + 32*i;
        const float4* V4 = (const float4*)(Vb + (size_t)b*BSTR_ + (size_t)l*STRIDE_ + h*D_);
        float4 a = V4[d8*2], c4 = V4[d8*2+1];
        acc[0] += a.x;  acc[1] += a.y;  acc[2] += a.z;  acc[3] += a.w;
        acc[4] += c4.x; acc[5] += c4.y; acc[6] += c4.z; acc[7] += c4.w;
    }
    __shared__ float red[32][64];
    #pragma unroll
    for (int j = 0; j < 8; j++) red[sub][d8*8+j] = acc[j];
    __syncthreads();
    if (threadIdx.x < 64){
        float s = 0.f;
        for (int k = 0; k < 32; k++) s += red[k][threadIdx.x];
        atomicAdd(&mean[bh*64 + threadIdx.x], s);
    }
}

// ---------- kernel D1: scores[bh][u][k] = scale * Q[qi_u]·K[k] ----------
__global__ __launch_bounds__(256) void kScores(const float* __restrict__ Qb,
                                               const float* __restrict__ Kb,
                                               const int* __restrict__ Mtop,
                                               float* __restrict__ scores){
    int bh = blockIdx.y, b = bh >> 3, h = bh & 7; int kc = blockIdx.x; // 16
    __shared__ float qs[U_][64];
    for (int t = threadIdx.x; t < U_*16; t += 256){
        int u = t >> 4, c = t & 15;
        int qi = Mtop[bh*U_ + u];
        float4 v = ((const float4*)(Qb + (size_t)b*BSTR_ + (size_t)qi*STRIDE_ + h*D_))[c];
        *(float4*)&qs[u][c*4] = v;
    }
    __syncthreads();
    int k = kc*256 + threadIdx.x;
    float4 kf[16];
    const float4* K4 = (const float4*)(Kb + (size_t)b*BSTR_ + (size_t)k*STRIDE_ + h*D_);
    #pragma unroll
    for (int c = 0; c < 16; c++) kf[c] = K4[c];
    for (int u = 0; u < U_; u++){
        const float4* qr = (const float4*)qs[u];
        float acc = 0.f;
        #pragma unroll
        for (int c = 0; c < 16; c++){
            float4 qv = qr[c];
            acc = fmaf(qv.x, kf[c].x, acc);
            acc = fmaf(qv.y, kf[c].y, acc);
            acc = fmaf(qv.z, kf[c].z, acc);
            acc = fmaf(qv.w, kf[c].w, acc);
        }
        scores[((size_t)(bh*U_ + u))*L_ + k] = acc * 0.125f;
    }
}

// ---------- kernel D2: softmax over k, in place ----------
__global__ __launch_bounds__(256) void kSoftmax(float* __restrict__ scores){
    int row = blockIdx.x; // 0..1439
    float* S = scores + (size_t)row * L_;
    float v[16];
    float mx = -1e30f;
    #pragma unroll
    for (int j = 0; j < 16; j++){ v[j] = S[threadIdx.x + 256*j]; mx = fmaxf(mx, v[j]); }
    for (int off = 32; off; off >>= 1) mx = fmaxf(mx, __shfl_xor(mx, off));
    __shared__ float wred[4];
    int w = threadIdx.x >> 6;
    if ((threadIdx.x & 63) == 0) wred[w] = mx;
    __syncthreads();
    mx = fmaxf(fmaxf(wred[0], wred[1]), fmaxf(wred[2], wred[3]));
    float sum = 0.f;
    #pragma unroll
    for (int j = 0; j < 16; j++){ v[j] = __expf(v[j] - mx); sum += v[j]; }
    for (int off = 32; off; off >>= 1) sum += __shfl_xor(sum, off);
    __syncthreads();                 // protect wred reuse
    if ((threadIdx.x & 63) == 0) wred[w] = sum;
    __syncthreads();
    float total = wred[0] + wred[1] + wred[2] + wred[3];
    float inv = 1.0f / total;
    #pragma unroll
    for (int j = 0; j < 16; j++) S[threadIdx.x + 256*j] = v[j] * inv;
}

// ---------- kernel D3: upd[bh][u][d] += P[bh][u][kchunk] @ V[kchunk][d] ----------
__global__ __launch_bounds__(256) void kPV(const float* __restrict__ Vb,
                                           const float* __restrict__ P,
                                           float* __restrict__ upd){
    int bh = blockIdx.y, b = bh >> 3, h = bh & 7; int kc = blockIdx.x; // 8 chunks x 512
    __shared__ float Pl[8][512];       // 16 KB
    __shared__ float red[4][8][64];    // 8 KB
    int d8 = threadIdx.x & 7, ks = threadIdx.x >> 3;  // ks 0..31
    int wv = threadIdx.x >> 6, lane = threadIdx.x & 63;

    for (int g = 0; g < 6; g++){
        int u0 = g*8; int nu = (U_ - u0 < 8) ? (U_ - u0) : 8;
        __syncthreads();   // previous iteration done with Pl/red
        for (int r = 0; r < nu; r++){
            const float* Pr = P + ((size_t)(bh*U_ + u0 + r))*L_ + kc*512;
            Pl[r][threadIdx.x]       = Pr[threadIdx.x];
            Pl[r][threadIdx.x + 256] = Pr[threadIdx.x + 256];
        }
        __syncthreads();

        float acc[8][8];
        #pragma unroll
        for (int r = 0; r < 8; r++)
            #pragma unroll
            for (int j = 0; j < 8; j++) acc[r][j] = 0.f;

        for (int i = 0; i < 16; i++){
            int k = ks + 32*i;
            const float4* V4 = (const float4*)(Vb + (size_t)b*BSTR_ +
                        (size_t)(kc*512 + k)*STRIDE_ + h*D_);
            float4 va = V4[d8*2], vb = V4[d8*2+1];
            float vf[8] = {va.x, va.y, va.z, va.w, vb.x, vb.y, vb.z, vb.w};
            #pragma unroll
            for (int r = 0; r < 8; r++){
                float p = Pl[r][k];
                #pragma unroll
                for (int j = 0; j < 8; j++) acc[r][j] = fmaf(p, vf[j], acc[r][j]);
            }
        }
        #pragma unroll
        for (int off = 8; off <= 32; off <<= 1)
            #pragma unroll
            for (int r = 0; r < 8; r++)
                #pragma unroll
                for (int j = 0; j < 8; j++) acc[r][j] += __shfl_xor(acc[r][j], off);
        if (lane < 8){
            for (int r = 0; r < 8; r++)
                #pragma unroll
                for (int j = 0; j < 8; j++) red[wv][r][d8*8+j] = acc[r][j];
        }
        __syncthreads();
        for (int t = threadIdx.x; t < nu*64; t += 256){
            int r = t >> 6, d = t & 63;
            float s = red[0][r][d] + red[1][r][d] + red[2][r][d] + red[3][r][d];
            atomicAdd(&upd[((size_t)(bh*U_) + u0 + r)*64 + d], s);
        }
    }
}

// ---------- kernel E: fill output with V-mean (mean buffer holds SUM; scale here) ----------
__global__ __launch_bounds__(256) void kFill(const float* __restrict__ mean,
                                             float* __restrict__ out){
    size_t t = (size_t)blockIdx.x*256 + threadIdx.x;   // one float4 each; 2,097,152 total
    int d16 = (int)(t & 15); int h = (int)((t >> 4) & 7); int b = (int)(t >> 19);
    int bh = b*8 + h;
    float4 o = *(const float4*)(mean + bh*64 + d16*4);
    const float inv = 1.0f / L_;
    o.x *= inv; o.y *= inv; o.z *= inv; o.w *= inv;
    ((float4*)out)[t] = o;
}

// ---------- kernel D4: scatter the 45 attended rows per (b,h) ----------
__global__ void kWriteRows(const float* __restrict__ upd,
                           const int* __restrict__ Mtop,
                           float* __restrict__ out){
    int bh = blockIdx.y, u = blockIdx.x; int b = bh >> 3, h = bh & 7;
    int qi = Mtop[bh*U_ + u];
    int d = threadIdx.x;  // 64
    float vv = upd[((size_t)(bh*U_) + u)*64 + d];
    out[(size_t)b*BSTR_ + (size_t)qi*STRIDE_ + h*D_ + d] = vv;
}

extern "C" void kernel_launch(void* const* d_in, const int* in_sizes, int n_in,
                              void* d_out, int out_size, void* d_ws, size_t ws_size,
                              hipStream_t stream) {
    const float* Qb  = (const float*)d_in[0];
    const float* Kb  = (const float*)d_in[1];
    const float* Vb  = (const float*)d_in[2];
    const int*   idx = (const int*)d_in[3];
    float* out = (float*)d_out;

    float* ws = (float*)d_ws;
    // ws layout (float offsets)
    float* scores   = ws;                         // 32*45*4096   = 5,898,240
    float* M        = ws + 5898240;               // 131072
    int*   Mtop     = (int*)(ws + 6029312);       // 1440 (pad to 2048)
    float* mean     = ws + 6031360;               // 2048 (holds SUM until kFill scales)
    float* upd      = ws + 6033408;               // 32*45*64 = 92160
    // total = 6,125,568 floats = 24.5 MB ; mean+upd contiguous for one kZero

    dim3 blk256(256);
    kZero     <<<dim3((2048+92160+255)/256), blk256, 0, stream>>>(mean, 2048+92160);
    kM        <<<dim3(2048),   blk256, 0, stream>>>(Qb, Kb, idx, M);
    kTop      <<<dim3(32),     blk256, 0, stream>>>(M, Mtop);
    kVsum     <<<dim3(16, 32), blk256, 0, stream>>>(Vb, mean);
    kScores   <<<dim3(16, 32), blk256, 0, stream>>>(Qb, Kb, Mtop, scores);
    kSoftmax  <<<dim3(1440),   blk256, 0, stream>>>(scores);
    kPV       <<<dim3(8, 32),  blk256, 0, stream>>>(Vb, scores, upd);
    kFill     <<<dim3(8192),   blk256, 0, stream>>>(mean, out);
    kWriteRows<<<dim3(45, 32), dim3(64), 0, stream>>>(upd, Mtop, out);
}